// Round 3
// baseline (333.684 us; speedup 1.0000x reference)
//
#include <hip/hip_runtime.h>
#include <math.h>
#include <stdint.h>

#define B_ 8
#define T_ 256
#define N_ 128
#define K_ 64

typedef const __attribute__((address_space(1))) uint32_t gu32_t;
typedef __attribute__((address_space(3))) uint32_t lu32_t;
// async global->LDS DMA, 16 B per lane; LDS dest = wave-uniform base + lane*16
#define DMA16(gp, lp) __builtin_amdgcn_global_load_lds((gu32_t*)(gp), (lu32_t*)(lp), 16, 0, 0)
#define FENCE() asm volatile("" ::: "memory")

// ---------------- Kernel 1: emission probabilities (softmax of obs @ W + b) ----------------
__global__ __launch_bounds__(128) void k_emit(
    const float* __restrict__ obs,    // [B,T,K]
    const int*   __restrict__ dur,    // [B]
    const float* __restrict__ W,      // [K,N]
    const float* __restrict__ bias,   // [N]
    float* __restrict__ e)            // [B,T,N] softmax probs
{
    int bt = blockIdx.x;
    int b  = bt >> 8;
    int t  = bt & 255;
    if (t >= dur[b]) return;
    int n = threadIdx.x;
    __shared__ float o[K_];
    __shared__ float wmax[2];
    __shared__ float wsum[2];
    if (n < K_) o[n] = obs[(size_t)bt * K_ + n];
    __syncthreads();
    float acc = bias[n];
    #pragma unroll
    for (int k = 0; k < K_; ++k)
        acc = fmaf(o[k], W[k * N_ + n], acc);
    float m = acc;
    #pragma unroll
    for (int off = 32; off; off >>= 1) m = fmaxf(m, __shfl_xor(m, off));
    int w = n >> 6;
    if ((n & 63) == 0) wmax[w] = m;
    __syncthreads();
    float M = fmaxf(wmax[0], wmax[1]);
    float ex = expf(acc - M);
    float s = ex;
    #pragma unroll
    for (int off = 32; off; off >>= 1) s += __shfl_xor(s, off);
    if ((n & 63) == 0) wsum[w] = s;
    __syncthreads();
    float S = wsum[0] + wsum[1];
    e[(size_t)bt * N_ + n] = ex / S;
}

// ---------------- Kernel 2a (primary): row-normalize tile -> bf16 ----------------
__device__ __forceinline__ uint32_t pack_bf16_2(float a, float b) {
    uint32_t ua = __float_as_uint(a); ua += 0x7fffu + ((ua >> 16) & 1u);
    uint32_t ub = __float_as_uint(b); ub += 0x7fffu + ((ub >> 16) & 1u);
    return (ua >> 16) | (ub & 0xffff0000u);
}

__global__ __launch_bounds__(256) void k_prep(
    const float* __restrict__ trans,  // [T,B,N,N]
    const int*   __restrict__ dur,
    uint32_t* __restrict__ tout)      // bf16 tiles [T,B,N,N], 32 KB each
{
    int tb = blockIdx.x;              // t*B + b
    int b  = tb & 7;
    int t  = tb >> 3;
    if (t >= dur[b]) return;
    int tid = threadIdx.x;            // 0..255
    const float4* tp = (const float4*)(trans + (size_t)tb * (N_ * N_));
    __shared__ float part[N_][33];
    __shared__ float sm_inv[N_];
    float4 v[16];
    #pragma unroll
    for (int i = 0; i < 16; ++i) v[i] = tp[tid + (i << 8)];
    #pragma unroll
    for (int i = 0; i < 16; ++i)
        part[(tid >> 5) + (i << 3)][tid & 31] = v[i].x + v[i].y + v[i].z + v[i].w;
    __syncthreads();
    if (tid < N_) {
        float s = 0.f;
        #pragma unroll
        for (int c = 0; c < 32; ++c) s += part[tid][c];
        sm_inv[tid] = 1.0f / s;
    }
    __syncthreads();
    uint2* op = (uint2*)tout + (size_t)tb * 4096;
    #pragma unroll
    for (int i = 0; i < 16; ++i) {
        float inv = sm_inv[(tid >> 5) + (i << 3)];
        uint2 o;
        o.x = pack_bf16_2(v[i].x * inv, v[i].y * inv);
        o.y = pack_bf16_2(v[i].z * inv, v[i].w * inv);
        op[tid + (i << 8)] = o;
    }
}

// ---------------- Kernel 2b (fallback): reciprocal row L1 sums ----------------
__global__ __launch_bounds__(256) void k_invl1(
    const float* __restrict__ trans,
    const int*   __restrict__ dur,
    float* __restrict__ invl1)        // [T,B,N]
{
    int tb = blockIdx.x;
    int b  = tb & 7;
    int t  = tb >> 3;
    if (t >= dur[b]) return;
    int tid = threadIdx.x;
    const float4* tp = (const float4*)(trans + (size_t)tb * (N_ * N_));
    __shared__ float part[N_][33];
    #pragma unroll
    for (int i = 0; i < 16; ++i) {
        float4 v = tp[tid + (i << 8)];
        part[(tid >> 5) + (i << 3)][tid & 31] = v.x + v.y + v.z + v.w;
    }
    __syncthreads();
    if (tid < N_) {
        float s = 0.f;
        #pragma unroll
        for (int c = 0; c < 32; ++c) s += part[tid][c];
        invl1[(size_t)tb * N_ + tid] = 1.0f / s;
    }
}

// ---------------- Kernel 3 (primary): serial forward recursion, bf16 tiles ----------------
// Invariant: y_j = exp(la_j - S). Per step: s_j = sum_k pp_k * That_kj ; y_j = e_j * s_j ;
// pp_next = y * rcp(Yhat_lagged); S -= log(rcp(Yhat)) [off critical path]. No exp/log in chain.
__global__ __launch_bounds__(512, 1) void k_fwd_bf16(
    const uint32_t* __restrict__ tiles, // bf16 [T,B,128,128], tile = 8192 u32
    const int*   __restrict__ dur,
    const float* __restrict__ sp,       // [B,N]
    const float* __restrict__ e,        // [B,T,N] probs
    float* __restrict__ out)            // [B]
{
    const int b    = blockIdx.x;
    const int tid  = threadIdx.x;
    const int lane = tid & 63;
    const int wv   = tid >> 6;
    const int g    = tid >> 5;        // k-group (8 rows)
    const int jq   = tid & 31;        // col quad
    const int r    = lane & 15;
    const int q    = lane >> 4;
    const int jrow = (wv << 4) + r;

    __shared__ __align__(16) uint32_t tile[3][8192];  // 3 x 32 KB
    __shared__ __align__(16) float part[16][132];
    __shared__ __align__(16) float ppl[N_];
    __shared__ __align__(16) float wmb[2][8];
    __shared__ __align__(16) float yf[N_];

    const int d = dur[b];
    const float4* pp4 = (const float4*)ppl;

#define DMA_TILE(c, tt) { \
    const uint32_t* g0_ = tiles + (((size_t)(tt) * B_ + b) << 13) + (wv << 10) + (lane << 2); \
    uint32_t* l0_ = &tile[c][wv << 10]; \
    DMA16(g0_,       l0_);       \
    DMA16(g0_ + 256, l0_ + 256); \
    DMA16(g0_ + 512, l0_ + 512); \
    DMA16(g0_ + 768, l0_ + 768); }

    // ---- bootstrap ----
    int t1 = (d > 1) ? 1 : 0;
    int t2 = (d > 2) ? 2 : d - 1;
    DMA_TILE(0, t1);
    FENCE();
    float e0  = e[((size_t)b * T_) * N_ + jrow];
    float sp0 = sp[b * N_ + jrow];
    float eC  = e[((size_t)b * T_ + t1) * N_ + jrow];
    FENCE();
    DMA_TILE(1, t2);

    float y = e0 * sp0;            // y at t=0, S=0
    float S = 0.f, Sout = 0.f;
    float4 ppq0, ppq1;

    if (d > 1) {
        float m = y;
        m = fmaxf(m, __shfl_xor(m, 1));
        m = fmaxf(m, __shfl_xor(m, 2));
        m = fmaxf(m, __shfl_xor(m, 4));
        m = fmaxf(m, __shfl_xor(m, 8));
        if (lane == 0) wmb[1][wv] = m;
        asm volatile("s_waitcnt lgkmcnt(0)" ::: "memory");
        __builtin_amdgcn_s_barrier();
        float4 wa = *(const float4*)&wmb[1][0];
        float4 wb = *(const float4*)&wmb[1][4];
        float Yh = fmaxf(fmaxf(fmaxf(wa.x, wa.y), fmaxf(wa.z, wa.w)),
                         fmaxf(fmaxf(wb.x, wb.y), fmaxf(wb.z, wb.w)));
        float rY = __builtin_amdgcn_rcpf(Yh);
        float ppv = y * rY;
        if (lane < 16) ppl[jrow] = ppv;
        ppq0 = pp4[2 * g];
        ppq1 = pp4[2 * g + 1];
        S -= __logf(rY);
    }

#define ROWFMA(KK, PK) { \
    uint2 rv_ = *(const uint2*)&tile[cur][(((g << 3) + KK) << 6) + (jq << 1)]; \
    sx = fmaf(PK, __uint_as_float(rv_.x << 16),         sx); \
    sy = fmaf(PK, __uint_as_float(rv_.x & 0xffff0000u), sy); \
    sz = fmaf(PK, __uint_as_float(rv_.y << 16),         sz); \
    sw = fmaf(PK, __uint_as_float(rv_.y & 0xffff0000u), sw); }

    int cur = 0;
    for (int t = 1; t < d; ++t) {
        // ---- phase B: e prefetch + tile(t+2) DMA (counts invariant), matvec from tile(t)
        int tn = (t + 1 < d) ? t + 1 : d - 1;
        float eN = e[((size_t)b * T_ + tn) * N_ + jrow];
        int fill = (cur == 0) ? 2 : cur - 1;
        int tf = (t + 2 < d) ? t + 2 : d - 1;
        DMA_TILE(fill, tf);
        asm volatile("s_waitcnt vmcnt(10)" ::: "memory");  // tile(t) landed (per-wave chunk)
        float sx = 0.f, sy = 0.f, sz = 0.f, sw = 0.f;
        ROWFMA(0, ppq0.x) ROWFMA(1, ppq0.y) ROWFMA(2, ppq0.z) ROWFMA(3, ppq0.w)
        ROWFMA(4, ppq1.x) ROWFMA(5, ppq1.y) ROWFMA(6, ppq1.z) ROWFMA(7, ppq1.w)
        *(float4*)&part[g][jq << 2] = make_float4(sx, sy, sz, sw);
        asm volatile("s_waitcnt lgkmcnt(0)" ::: "memory");
        __builtin_amdgcn_s_barrier();

        // ---- phase C: combine, y, lagged global max, next pp
        float p0 = part[(q << 2) + 0][jrow] + part[(q << 2) + 1][jrow]
                 + part[(q << 2) + 2][jrow] + part[(q << 2) + 3][jrow];
        p0 += __shfl_xor(p0, 16);
        p0 += __shfl_xor(p0, 32);
        y = p0 * eC;
        float m = y;
        m = fmaxf(m, __shfl_xor(m, 1));
        m = fmaxf(m, __shfl_xor(m, 2));
        m = fmaxf(m, __shfl_xor(m, 4));
        m = fmaxf(m, __shfl_xor(m, 8));
        float4 wa = *(const float4*)&wmb[t & 1][0];
        float4 wb = *(const float4*)&wmb[t & 1][4];
        float Yh = fmaxf(fmaxf(fmaxf(wa.x, wa.y), fmaxf(wa.z, wa.w)),
                         fmaxf(fmaxf(wb.x, wb.y), fmaxf(wb.z, wb.w)));
        if (lane == 0) wmb[(t + 1) & 1][wv] = m;
        float rY = __builtin_amdgcn_rcpf(Yh);
        float ppv = y * rY;
        if (lane < 16) ppl[jrow] = ppv;
        ppq0 = pp4[2 * g];
        ppq1 = pp4[2 * g + 1];
        Sout = S;                 // S matching current y
        S -= __logf(rY);          // off critical path
        eC = eN;
        asm volatile("s_waitcnt lgkmcnt(0)" ::: "memory");
        __builtin_amdgcn_s_barrier();
        cur = (cur == 2) ? 0 : cur + 1;
    }

    // ---- final: out[b] = Sout + log(sum_j y_j)
    if (lane < 16) yf[jrow] = y;
    asm volatile("s_waitcnt lgkmcnt(0)" ::: "memory");
    __builtin_amdgcn_s_barrier();
    if (tid < 64) {
        float s = yf[tid] + yf[tid + 64];
        #pragma unroll
        for (int off = 32; off; off >>= 1) s += __shfl_xor(s, off);
        if (tid == 0) out[b] = Sout + logf(s);
    }
#undef DMA_TILE
#undef ROWFMA
}

// ---------------- Kernel 3 (fallback): fp32 tiles straight from trans ----------------
__global__ __launch_bounds__(512, 1) void k_fwd_f32(
    const float* __restrict__ trans,  // [T,B,N,N]
    const int*   __restrict__ dur,
    const float* __restrict__ sp,
    const float* __restrict__ e,      // probs
    const float* __restrict__ invl1,  // [T,B,N]
    float* __restrict__ out)
{
    const int b    = blockIdx.x;
    const int tid  = threadIdx.x;
    const int lane = tid & 63;
    const int wv   = tid >> 6;
    const int g    = tid >> 5;
    const int jq   = tid & 31;
    const int r    = lane & 15;
    const int q    = lane >> 4;
    const int jrow = (wv << 4) + r;

    __shared__ __align__(16) float tileF[2][16384];   // 2 x 64 KB
    __shared__ __align__(16) float part[16][132];
    __shared__ __align__(16) float ppl[N_];
    __shared__ __align__(16) float wmb[2][8];
    __shared__ __align__(16) float yf[N_];

    const int d = dur[b];
    const float4* pp4 = (const float4*)ppl;

#define DMA_TILEF(c, tt) { \
    const uint32_t* g0_ = (const uint32_t*)trans + (((size_t)(tt) * B_ + b) << 14) + (wv << 11) + (lane << 2); \
    uint32_t* l0_ = (uint32_t*)&tileF[c][wv << 11]; \
    DMA16(g0_,        l0_);        DMA16(g0_ + 256,  l0_ + 256); \
    DMA16(g0_ + 512,  l0_ + 512);  DMA16(g0_ + 768,  l0_ + 768); \
    DMA16(g0_ + 1024, l0_ + 1024); DMA16(g0_ + 1280, l0_ + 1280); \
    DMA16(g0_ + 1536, l0_ + 1536); DMA16(g0_ + 1792, l0_ + 1792); }

    int t1 = (d > 1) ? 1 : 0;
    int t2 = (d > 2) ? 2 : d - 1;
    DMA_TILEF(0, t1);
    FENCE();
    float e0   = e[((size_t)b * T_) * N_ + jrow];
    float sp0  = sp[b * N_ + jrow];
    float eC   = e[((size_t)b * T_ + t1) * N_ + jrow];
    float invB = invl1[((size_t)t1 * B_ + b) * N_ + jrow];
    float invC = invl1[((size_t)t2 * B_ + b) * N_ + jrow];
    FENCE();

    float y = e0 * sp0;
    float S = 0.f, Sout = 0.f;
    float4 ppq0, ppq1;

    if (d > 1) {
        float m = y;
        m = fmaxf(m, __shfl_xor(m, 1));
        m = fmaxf(m, __shfl_xor(m, 2));
        m = fmaxf(m, __shfl_xor(m, 4));
        m = fmaxf(m, __shfl_xor(m, 8));
        if (lane == 0) wmb[1][wv] = m;
        asm volatile("s_waitcnt lgkmcnt(0)" ::: "memory");
        __builtin_amdgcn_s_barrier();
        float4 wa = *(const float4*)&wmb[1][0];
        float4 wb = *(const float4*)&wmb[1][4];
        float Yh = fmaxf(fmaxf(fmaxf(wa.x, wa.y), fmaxf(wa.z, wa.w)),
                         fmaxf(fmaxf(wb.x, wb.y), fmaxf(wb.z, wb.w)));
        float rY = __builtin_amdgcn_rcpf(Yh);
        float ppv = y * rY * invB;
        if (lane < 16) ppl[jrow] = ppv;
        ppq0 = pp4[2 * g];
        ppq1 = pp4[2 * g + 1];
        S -= __logf(rY);
    }

#define ROWFMAF(KK, PK) { \
    float4 rv_ = *(const float4*)&tileF[cur][(((g << 3) + KK) << 7) + (jq << 2)]; \
    sx = fmaf(PK, rv_.x, sx); sy = fmaf(PK, rv_.y, sy); \
    sz = fmaf(PK, rv_.z, sz); sw = fmaf(PK, rv_.w, sw); }

    int cur = 0;
    for (int t = 1; t < d; ++t) {
        int tn = (t + 1 < d) ? t + 1 : d - 1;
        float eN = e[((size_t)b * T_ + tn) * N_ + jrow];
        int ti = (t + 2 < d) ? t + 2 : d - 1;
        float invN = invl1[((size_t)ti * B_ + b) * N_ + jrow];
        int tf = (t + 1 < d) ? t + 1 : d - 1;
        DMA_TILEF(cur ^ 1, tf);
        asm volatile("s_waitcnt vmcnt(10)" ::: "memory");
        float sx = 0.f, sy = 0.f, sz = 0.f, sw = 0.f;
        ROWFMAF(0, ppq0.x) ROWFMAF(1, ppq0.y) ROWFMAF(2, ppq0.z) ROWFMAF(3, ppq0.w)
        ROWFMAF(4, ppq1.x) ROWFMAF(5, ppq1.y) ROWFMAF(6, ppq1.z) ROWFMAF(7, ppq1.w)
        *(float4*)&part[g][jq << 2] = make_float4(sx, sy, sz, sw);
        asm volatile("s_waitcnt lgkmcnt(0)" ::: "memory");
        __builtin_amdgcn_s_barrier();

        float p0 = part[(q << 2) + 0][jrow] + part[(q << 2) + 1][jrow]
                 + part[(q << 2) + 2][jrow] + part[(q << 2) + 3][jrow];
        p0 += __shfl_xor(p0, 16);
        p0 += __shfl_xor(p0, 32);
        y = p0 * eC;
        float m = y;
        m = fmaxf(m, __shfl_xor(m, 1));
        m = fmaxf(m, __shfl_xor(m, 2));
        m = fmaxf(m, __shfl_xor(m, 4));
        m = fmaxf(m, __shfl_xor(m, 8));
        float4 wa = *(const float4*)&wmb[t & 1][0];
        float4 wb = *(const float4*)&wmb[t & 1][4];
        float Yh = fmaxf(fmaxf(fmaxf(wa.x, wa.y), fmaxf(wa.z, wa.w)),
                         fmaxf(fmaxf(wb.x, wb.y), fmaxf(wb.z, wb.w)));
        if (lane == 0) wmb[(t + 1) & 1][wv] = m;
        float rY = __builtin_amdgcn_rcpf(Yh);
        float ppv = y * rY * invC;
        if (lane < 16) ppl[jrow] = ppv;
        ppq0 = pp4[2 * g];
        ppq1 = pp4[2 * g + 1];
        Sout = S;
        S -= __logf(rY);
        eC = eN;
        invC = invN;
        asm volatile("s_waitcnt lgkmcnt(0)" ::: "memory");
        __builtin_amdgcn_s_barrier();
        cur ^= 1;
    }

    if (lane < 16) yf[jrow] = y;
    asm volatile("s_waitcnt lgkmcnt(0)" ::: "memory");
    __builtin_amdgcn_s_barrier();
    if (tid < 64) {
        float s = yf[tid] + yf[tid + 64];
        #pragma unroll
        for (int off = 32; off; off >>= 1) s += __shfl_xor(s, off);
        if (tid == 0) out[b] = Sout + logf(s);
    }
#undef DMA_TILEF
#undef ROWFMAF
}

extern "C" void kernel_launch(void* const* d_in, const int* in_sizes, int n_in,
                              void* d_out, int out_size, void* d_ws, size_t ws_size,
                              hipStream_t stream) {
    const float* obs   = (const float*)d_in[0];
    const int*   dur   = (const int*)  d_in[1];
    const float* trans = (const float*)d_in[2];
    const float* sp    = (const float*)d_in[3];
    const float* W     = (const float*)d_in[4];
    const float* bias  = (const float*)d_in[5];
    float* out = (float*)d_out;

    float* e = (float*)d_ws;                               // B*T*N fp32 = 1 MB
    const size_t eBytes = (size_t)B_ * T_ * N_ * 4;
    const size_t tileBytes = (size_t)T_ * B_ * N_ * N_ * 2; // 64 MB bf16

    hipLaunchKernelGGL(k_emit, dim3(B_ * T_), dim3(128), 0, stream, obs, dur, W, bias, e);

    if (ws_size >= eBytes + tileBytes) {
        uint32_t* tiles = (uint32_t*)((char*)d_ws + eBytes);
        hipLaunchKernelGGL(k_prep, dim3(T_ * B_), dim3(256), 0, stream, trans, dur, tiles);
        hipLaunchKernelGGL(k_fwd_bf16, dim3(B_), dim3(512), 0, stream, tiles, dur, sp, e, out);
    } else {
        float* invl1 = (float*)((char*)d_ws + eBytes);     // T*B*N fp32 = 1 MB
        hipLaunchKernelGGL(k_invl1, dim3(T_ * B_), dim3(256), 0, stream, trans, dur, invl1);
        hipLaunchKernelGGL(k_fwd_f32, dim3(B_), dim3(512), 0, stream, trans, dur, sp, e, invl1, out);
    }
}

// Round 5
// 105.417 us; speedup vs baseline: 3.1654x; 3.1654x over previous
//
#include <hip/hip_runtime.h>
#include <math.h>
#include <stdint.h>

#define B_ 8
#define T_ 256
#define N_ 128
#define K_ 64
#define NCH 32
#define LOG128 4.852030263919617f
#define STRIDE_B 4128   // padded 16-col-block / strip stride in bytes (breaks bank phase)

typedef __attribute__((ext_vector_type(2))) unsigned int u32x2;
typedef __attribute__((ext_vector_type(4))) unsigned int u32x4;
typedef __attribute__((ext_vector_type(4))) float f32x4;
typedef __attribute__((ext_vector_type(8))) short short8;

__device__ __forceinline__ uint32_t cvtpk(float lo, float hi) {
    uint32_t r;
    asm("v_cvt_pk_bf16_f32 %0, %1, %2" : "=v"(r) : "v"(lo), "v"(hi));
    return r;
}
__device__ __forceinline__ float blo(uint32_t w) { return __uint_as_float(w << 16); }
__device__ __forceinline__ float bhi(uint32_t w) { return __uint_as_float(w & 0xffff0000u); }

// ---------------- Kernel 1: emission probabilities (softmax of obs @ W + b) ----------------
__global__ __launch_bounds__(128) void k_emit(
    const float* __restrict__ obs,    // [B,T,K]
    const int*   __restrict__ dur,    // [B]
    const float* __restrict__ W,      // [K,N]
    const float* __restrict__ bias,   // [N]
    float* __restrict__ e)            // [B,T,N] softmax probs
{
    int bt = blockIdx.x;
    int b  = bt >> 8;
    int t  = bt & 255;
    if (t >= dur[b]) return;
    int n = threadIdx.x;
    __shared__ float o[K_];
    __shared__ float wmax[2];
    __shared__ float wsum[2];
    if (n < K_) o[n] = obs[(size_t)bt * K_ + n];
    __syncthreads();
    float acc = bias[n];
    #pragma unroll
    for (int k = 0; k < K_; ++k)
        acc = fmaf(o[k], W[k * N_ + n], acc);
    float m = acc;
    #pragma unroll
    for (int off = 32; off; off >>= 1) m = fmaxf(m, __shfl_xor(m, off));
    int w = n >> 6;
    if ((n & 63) == 0) wmax[w] = m;
    __syncthreads();
    float M = fmaxf(wmax[0], wmax[1]);
    float ex = expf(acc - M);
    float s = ex;
    #pragma unroll
    for (int off = 32; off; off >>= 1) s += __shfl_xor(s, off);
    if ((n & 63) == 0) wsum[w] = s;
    __syncthreads();
    float S = wsum[0] + wsum[1];
    e[(size_t)bt * N_ + n] = ex / S;
}

// ---------------- Kernel 2: chunk matrix products via MFMA ----------------
// Block (b,c): G_c = Prod_{t=t0..te} C_t, C_t = 128*diag(e[t-1])*rownorm(trans[t,b]).
// gamma recursion: gamma_t = gamma_{t-1} @ C_t (gamma = alpha/e elementwise).
// Wave wv owns G rows [16wv,16wv+16), kept as bf16 strip[k][m] (k*16+m, 16-wide rows)
// so ds_read_b64_tr_b16 (4 bf16 at +32B stride) yields the exact MFMA A-fragment.
// C' stored as 8 column-blocks [jb][k][16] (stride 4128B) -> same tr pattern = B-fragment.
// Output: G row-major bf16 [128][128] per (b,c).
__global__ __launch_bounds__(512, 1) void k_chunk(
    const float* __restrict__ trans,  // [T,B,N,N]
    const int*   __restrict__ dur,
    const float* __restrict__ e,      // [B,T,N]
    uint32_t* __restrict__ gout)      // [B][NCH][8192] u32
{
    const int bc = blockIdx.x;
    const int b  = bc & 7;
    const int c  = bc >> 3;
    const int d  = dur[b];
    const int t0 = c * 8 + 1;
    if (t0 > d - 1) return;
    int te = c * 8 + 8; if (te > d - 1) te = d - 1;

    const int tid  = threadIdx.x;
    const int lane = tid & 63;
    const int wv   = tid >> 6;
    const int cc   = lane & 15;
    const int gq   = lane >> 4;

    __shared__ __align__(16) uint8_t ldsC[8 * STRIDE_B];    // C' col-blocks, 33 KB
    __shared__ __align__(16) uint8_t strips[8 * STRIDE_B];  // per-wave G strips, 33 KB
    __shared__ __align__(16) float part[N_][36];            // stride 36: f4-aligned
    __shared__ float inv[N_];

    // ---- strip init: G = Identity. strip[k][m] = G[16wv+m][k] = delta(16wv+m, k)
    {
        uint32_t* sw = (uint32_t*)(strips + wv * STRIDE_B);
        #pragma unroll
        for (int i = 0; i < 16; ++i) sw[lane + i * 64] = 0;  // zero 4096B used area
        if (lane < 16)
            ((uint16_t*)(strips + wv * STRIDE_B))[(16 * wv + lane) * 16 + lane] = 0x3F80u;
    }

    const uint32_t cbase = (uint32_t)(uintptr_t)&ldsC[0];
    const uint32_t sbase = (uint32_t)(uintptr_t)&strips[wv * STRIDE_B];
    const uint32_t lt    = (uint32_t)(cc * 2 + gq * 256);   // (cc + gq*128) elems * 2B

    f32x4 acc[8];

    for (int t = t0; t <= te; ++t) {
        // ---------- stage: coalesced load, row L1 sums, scale by 128*e/rowsum, pack bf16
        const float4* gp = (const float4*)(trans + (((size_t)t * B_ + b) << 14));
        float4 v[8];
        #pragma unroll
        for (int i = 0; i < 8; ++i) v[i] = gp[tid + i * 512];
        #pragma unroll
        for (int i = 0; i < 8; ++i)
            part[(tid >> 5) + i * 16][tid & 31] = (v[i].x + v[i].y) + (v[i].z + v[i].w);
        __syncthreads();
        if (tid < N_) {
            float s = 0.f;
            #pragma unroll
            for (int q2 = 0; q2 < 8; ++q2) {
                float4 p4 = *(const float4*)&part[tid][q2 * 4];
                s += (p4.x + p4.y) + (p4.z + p4.w);
            }
            inv[tid] = 128.0f * e[((size_t)b * T_ + (t - 1)) * N_ + tid] / s;
        }
        __syncthreads();
        #pragma unroll
        for (int i = 0; i < 8; ++i) {
            int row = (tid >> 5) + i * 16;               // k
            int jb  = (tid & 31) >> 2;                   // 16-col block
            int cc0 = (tid & 3) << 2;                    // col within block (quad)
            float sc = inv[row];
            uint32_t p0 = cvtpk(v[i].x * sc, v[i].y * sc);
            uint32_t p1 = cvtpk(v[i].z * sc, v[i].w * sc);
            *(uint2*)(ldsC + jb * STRIDE_B + row * 32 + cc0 * 2) = make_uint2(p0, p1);
        }
        __syncthreads();

        // ---------- A fragments: lane gets strip[k = kb*32+gq*8+j][m = cc], j=0..7
        u32x2 a0[4], a1[4];
        #pragma unroll
        for (int kb = 0; kb < 4; ++kb) {
            uint32_t ad = sbase + (uint32_t)(kb * 1024) + lt;
            asm volatile("ds_read_b64_tr_b16 %0, %1" : "=v"(a0[kb]) : "v"(ad)       : "memory");
            asm volatile("ds_read_b64_tr_b16 %0, %1" : "=v"(a1[kb]) : "v"(ad + 128) : "memory");
        }
        asm volatile("s_waitcnt lgkmcnt(0)" ::: "memory");
        __builtin_amdgcn_sched_barrier(0);
        short8 A[4];
        #pragma unroll
        for (int kb = 0; kb < 4; ++kb) {
            u32x4 tmp = (u32x4){a0[kb].x, a0[kb].y, a1[kb].x, a1[kb].y};
            A[kb] = __builtin_bit_cast(short8, tmp);
        }

        // ---------- D = G_old x C' : 8 jb-blocks x 4 K-slices
        #pragma unroll
        for (int jb = 0; jb < 8; ++jb) {
            u32x2 b0[4], b1[4];
            #pragma unroll
            for (int kb = 0; kb < 4; ++kb) {
                uint32_t bd = cbase + (uint32_t)(jb * STRIDE_B + kb * 1024) + lt;
                asm volatile("ds_read_b64_tr_b16 %0, %1" : "=v"(b0[kb]) : "v"(bd)       : "memory");
                asm volatile("ds_read_b64_tr_b16 %0, %1" : "=v"(b1[kb]) : "v"(bd + 128) : "memory");
            }
            asm volatile("s_waitcnt lgkmcnt(0)" ::: "memory");
            __builtin_amdgcn_sched_barrier(0);
            f32x4 d4 = (f32x4){0.f, 0.f, 0.f, 0.f};
            #pragma unroll
            for (int kb = 0; kb < 4; ++kb) {
                u32x4 tmp = (u32x4){b0[kb].x, b0[kb].y, b1[kb].x, b1[kb].y};
                short8 Bf = __builtin_bit_cast(short8, tmp);
                d4 = __builtin_amdgcn_mfma_f32_16x16x32_bf16(A[kb], Bf, d4, 0, 0, 0);
            }
            acc[jb] = d4;
        }

        // ---------- strip <- G_new (wave-private). D layout: row=(gq*4+r), col=cc (m89).
        // strip[j = jb*16+cc][m = gq*4+r], elem = j*16+m -> byte = j*32 + gq*8 + 2r
        #pragma unroll
        for (int jb = 0; jb < 8; ++jb) {
            uint32_t p0 = cvtpk(acc[jb][0], acc[jb][1]);
            uint32_t p1 = cvtpk(acc[jb][2], acc[jb][3]);
            *(uint2*)(strips + wv * STRIDE_B + (jb * 16 + cc) * 32 + gq * 8) = make_uint2(p0, p1);
        }
        __syncthreads();   // all waves done reading ldsC before next staging overwrite
    }

    // ---------- export G row-major bf16: tr_read own strip -> b128 global stores
    uint32_t* gdst = gout + ((size_t)(b * NCH + c) << 13);
    #pragma unroll
    for (int kb = 0; kb < 4; ++kb) {
        u32x2 e0, e1;
        uint32_t ad = sbase + (uint32_t)(kb * 1024) + lt;
        asm volatile("ds_read_b64_tr_b16 %0, %1" : "=v"(e0) : "v"(ad)       : "memory");
        asm volatile("ds_read_b64_tr_b16 %0, %1" : "=v"(e1) : "v"(ad + 128) : "memory");
        asm volatile("s_waitcnt lgkmcnt(0)" ::: "memory");
        __builtin_amdgcn_sched_barrier(0);
        u32x4 o = (u32x4){e0.x, e0.y, e1.x, e1.y};
        // lane holds G[16wv+cc][kb*32+gq*8 .. +7] -> u32 idx = row*64 + kb*16 + gq*4
        *(u32x4*)(gdst + (size_t)((16 * wv + cc) * 64 + kb * 16 + gq * 4)) = o;
    }
}

// ---------------- Kernel 3: serial combine, 1 wave per batch ----------------
// gamma (128 f32, 2/lane) <- gamma @ G_c, rescale by max (exact: S -= log(mr) for any mr).
__global__ __launch_bounds__(64, 1) void k_comb(
    const uint32_t* __restrict__ gtiles, // [B][NCH][8192] u32, G row-major bf16
    const int*   __restrict__ dur,
    const float* __restrict__ sp,        // [B,N]
    const float* __restrict__ e,         // [B,T,N]
    float* __restrict__ out)             // [B]
{
    const int b = blockIdx.x;
    const int l = threadIdx.x;
    const int d = dur[b];
    const int nc = (d - 1 + 7) >> 3;
    __shared__ float gl[N_];

    float g0 = sp[b * N_ + 2 * l];
    float g1 = sp[b * N_ + 2 * l + 1];
    float S  = -(float)(d - 1) * LOG128;

    for (int c = 0; c < nc; ++c) {
        const uint32_t* gp = gtiles + (((size_t)b * NCH + c) << 13) + l;
        uint32_t colw[128];                       // G[k][2l], G[k][2l+1] per k (static idx)
        #pragma unroll
        for (int k = 0; k < 128; ++k) colw[k] = gp[(size_t)k * 64];
        *(float2*)&gl[2 * l] = make_float2(g0, g1);   // single wave: lockstep, in-order LDS
        float n0 = 0.f, n1 = 0.f;
        #pragma unroll
        for (int kq = 0; kq < 32; ++kq) {
            float4 gv = *(const float4*)&gl[kq * 4];  // uniform addr -> broadcast
            uint32_t w0 = colw[4 * kq],     w1 = colw[4 * kq + 1];
            uint32_t w2 = colw[4 * kq + 2], w3 = colw[4 * kq + 3];
            n0 = fmaf(blo(w0), gv.x, n0); n1 = fmaf(bhi(w0), gv.x, n1);
            n0 = fmaf(blo(w1), gv.y, n0); n1 = fmaf(bhi(w1), gv.y, n1);
            n0 = fmaf(blo(w2), gv.z, n0); n1 = fmaf(bhi(w2), gv.z, n1);
            n0 = fmaf(blo(w3), gv.w, n0); n1 = fmaf(bhi(w3), gv.w, n1);
        }
        float mx = fmaxf(n0, n1);
        #pragma unroll
        for (int of = 1; of < 64; of <<= 1) mx = fmaxf(mx, __shfl_xor(mx, of));
        float mr = __builtin_amdgcn_rcpf(mx);
        g0 = n0 * mr; g1 = n1 * mr;
        S -= __logf(mr);
    }

    float e0 = e[((size_t)b * T_ + (d - 1)) * N_ + 2 * l];
    float e1 = e[((size_t)b * T_ + (d - 1)) * N_ + 2 * l + 1];
    float sv = g0 * e0 + g1 * e1;
    #pragma unroll
    for (int of = 1; of < 64; of <<= 1) sv += __shfl_xor(sv, of);
    if (l == 0) out[b] = S + logf(sv);
}

extern "C" void kernel_launch(void* const* d_in, const int* in_sizes, int n_in,
                              void* d_out, int out_size, void* d_ws, size_t ws_size,
                              hipStream_t stream) {
    const float* obs   = (const float*)d_in[0];   // [B,T,K]
    const int*   dur   = (const int*)  d_in[1];   // [B]
    const float* trans = (const float*)d_in[2];   // [T,B,N,N]
    const float* sp    = (const float*)d_in[3];   // [B,N]
    const float* W     = (const float*)d_in[4];   // [K,N]
    const float* bias  = (const float*)d_in[5];   // [N]
    float* out = (float*)d_out;

    float* e = (float*)d_ws;                                   // 1 MB
    uint32_t* gout = (uint32_t*)((char*)d_ws + (size_t)B_ * T_ * N_ * 4);  // 8 MB

    hipLaunchKernelGGL(k_emit,  dim3(B_ * T_),  dim3(128), 0, stream, obs, dur, W, bias, e);
    hipLaunchKernelGGL(k_chunk, dim3(B_ * NCH), dim3(512), 0, stream, trans, dur, e, gout);
    hipLaunchKernelGGL(k_comb,  dim3(B_),       dim3(64),  0, stream, gout, dur, sp, e, out);
}

// Round 8
// 70.175 us; speedup vs baseline: 4.7550x; 1.5022x over previous
//
#include <hip/hip_runtime.h>
#include <math.h>
#include <stdint.h>

#define B_ 8
#define T_ 256
#define N_ 128
#define K_ 64
#define NCH 32
#define LOG128 4.852030263919617f
#define STRIDE_S 4128   // padded 16-col-block / strip stride in bytes

typedef __attribute__((ext_vector_type(2))) unsigned int u32x2;
typedef __attribute__((ext_vector_type(4))) unsigned int u32x4;
typedef __attribute__((ext_vector_type(4))) float f32x4;
typedef __attribute__((ext_vector_type(8))) short short8;

__device__ __forceinline__ uint32_t cvtpk(float lo, float hi) {
    uint32_t r;
    asm("v_cvt_pk_bf16_f32 %0, %1, %2" : "=v"(r) : "v"(lo), "v"(hi));
    return r;
}
__device__ __forceinline__ float blo(uint32_t w) { return __uint_as_float(w << 16); }
__device__ __forceinline__ float bhi(uint32_t w) { return __uint_as_float(w & 0xffff0000u); }

#define TRRD(dst, addr) asm volatile("ds_read_b64_tr_b16 %0, %1" : "=v"(dst) : "v"(addr) : "memory")
// lgkmcnt is a 4-bit field: counts must be <= 15
#define WAITL8  { asm volatile("s_waitcnt lgkmcnt(8)"  ::: "memory"); __builtin_amdgcn_sched_barrier(0); }
#define WAITL0  { asm volatile("s_waitcnt lgkmcnt(0)"  ::: "memory"); __builtin_amdgcn_sched_barrier(0); }

// ---------------- Kernel 1: emission probabilities (softmax of obs @ W + b) ----------------
__global__ __launch_bounds__(128) void k_emit(
    const float* __restrict__ obs,    // [B,T,K]
    const int*   __restrict__ dur,    // [B]
    const float* __restrict__ W,      // [K,N]
    const float* __restrict__ bias,   // [N]
    float* __restrict__ e)            // [B,T,N] softmax probs
{
    int bt = blockIdx.x;
    int b  = bt >> 8;
    int t  = bt & 255;
    if (t >= dur[b]) return;
    int n = threadIdx.x;
    __shared__ float o[K_];
    __shared__ float wmax[2];
    __shared__ float wsum[2];
    if (n < K_) o[n] = obs[(size_t)bt * K_ + n];
    __syncthreads();
    float acc = bias[n];
    #pragma unroll
    for (int k = 0; k < K_; ++k)
        acc = fmaf(o[k], W[k * N_ + n], acc);
    float m = acc;
    #pragma unroll
    for (int off = 32; off; off >>= 1) m = fmaxf(m, __shfl_xor(m, off));
    int w = n >> 6;
    if ((n & 63) == 0) wmax[w] = m;
    __syncthreads();
    float M = fmaxf(wmax[0], wmax[1]);
    float ex = expf(acc - M);
    float s = ex;
    #pragma unroll
    for (int off = 32; off; off >>= 1) s += __shfl_xor(s, off);
    if ((n & 63) == 0) wsum[w] = s;
    __syncthreads();
    float S = wsum[0] + wsum[1];
    e[(size_t)bt * N_ + n] = ex / S;
}

// ---------------- Kernel 2: chunk matrix products via MFMA ----------------
// Block (b,c): G_c = Prod_{t=t0..te} C_t, C_t = 128*diag(e[t-1])*rownorm(trans[t,b]).
// Math/layout identical to the round-5 verified kernel; 1 barrier/step
// (shfl row-sums, double-buffered ldsC, reg prefetch) and a 2-deep
// counted-lgkmcnt tr_read pipeline in the MFMA phase.
__global__ __launch_bounds__(512, 1) void k_chunk(
    const float* __restrict__ trans,  // [T,B,N,N]
    const int*   __restrict__ dur,
    const float* __restrict__ e,      // [B,T,N]
    uint32_t* __restrict__ gout)      // [B][NCH][8192] u32
{
    const int bc = blockIdx.x;
    const int b  = bc & 7;
    const int c  = bc >> 3;
    const int d  = dur[b];
    const int t0 = c * 8 + 1;
    if (t0 > d - 1) return;
    int te = c * 8 + 8; if (te > d - 1) te = d - 1;

    const int tid  = threadIdx.x;
    const int lane = tid & 63;
    const int wv   = tid >> 6;
    const int cc   = lane & 15;
    const int gq   = lane >> 4;

    __shared__ __align__(16) uint8_t ldsC[2][8 * STRIDE_S];  // C' col-blocks, double-buffered
    __shared__ __align__(16) uint8_t strips[8 * STRIDE_S];   // per-wave G strips

    // strip init: G = Identity. strip[k][m] = G[16wv+m][k]
    {
        uint32_t* sw = (uint32_t*)(strips + wv * STRIDE_S);
        #pragma unroll
        for (int i = 0; i < 16; ++i) sw[lane + i * 64] = 0;
        if (lane < 16)
            ((uint16_t*)(strips + wv * STRIDE_S))[(16 * wv + lane) * 16 + lane] = 0x3F80u;
    }

    const uint32_t sbase = (uint32_t)(uintptr_t)&strips[wv * STRIDE_S];
    const uint32_t lt    = (uint32_t)(cc * 2 + gq * 256);
    const int row0 = tid >> 5;                 // rows row0 + 16i
    const int jbp  = (tid & 31) >> 2;          // pack col-block
    const int cc0  = (tid & 3) << 2;           // pack col quad

    f32x4 acc[8];

    // preload v, e for t0
    float4 v[8];
    float  ev[8];
    {
        const float4* gp = (const float4*)(trans + (((size_t)t0 * B_ + b) << 14));
        #pragma unroll
        for (int i = 0; i < 8; ++i) v[i] = gp[tid + i * 512];
        #pragma unroll
        for (int i = 0; i < 8; ++i)
            ev[i] = e[((size_t)b * T_ + (t0 - 1)) * N_ + row0 + i * 16];
    }

    int buf = 0;
    for (int t = t0; t <= te; ++t, buf ^= 1) {
        uint8_t* cb = ldsC[buf];
        const uint32_t cbase = (uint32_t)(uintptr_t)cb;

        // ---- row L1 sums via 32-lane shuffle; inv = 128*e/rowsum; pack bf16 to ldsC[buf]
        #pragma unroll
        for (int i = 0; i < 8; ++i) {
            float ps = (v[i].x + v[i].y) + (v[i].z + v[i].w);
            ps += __shfl_xor(ps, 1);
            ps += __shfl_xor(ps, 2);
            ps += __shfl_xor(ps, 4);
            ps += __shfl_xor(ps, 8);
            ps += __shfl_xor(ps, 16);
            float sc = 128.0f * ev[i] / ps;
            uint32_t p0 = cvtpk(v[i].x * sc, v[i].y * sc);
            uint32_t p1 = cvtpk(v[i].z * sc, v[i].w * sc);
            *(uint2*)(cb + jbp * STRIDE_S + (row0 + i * 16) * 32 + cc0 * 2) = make_uint2(p0, p1);
        }

        // ---- prefetch v, e for t+1 (before the barrier so it can't sink past it)
        if (t < te) {
            const float4* gp = (const float4*)(trans + (((size_t)(t + 1) * B_ + b) << 14));
            #pragma unroll
            for (int i = 0; i < 8; ++i) v[i] = gp[tid + i * 512];
            #pragma unroll
            for (int i = 0; i < 8; ++i)
                ev[i] = e[((size_t)b * T_ + t) * N_ + row0 + i * 16];
        }
        __syncthreads();

        // ---- MFMA phase: A from own strip, B from ldsC[buf]; 2-deep tr_read pipeline
        u32x2 ra[8];
        #pragma unroll
        for (int kb = 0; kb < 4; ++kb) {
            uint32_t ad = sbase + (uint32_t)(kb * 1024) + lt;
            TRRD(ra[2 * kb],     ad);
            TRRD(ra[2 * kb + 1], ad + 128);
        }
        u32x2 rb[2][8];
#define ISSUE_B(S, JB) { \
        _Pragma("unroll") \
        for (int kb = 0; kb < 4; ++kb) { \
            uint32_t bd = cbase + (uint32_t)((JB) * STRIDE_S + kb * 1024) + lt; \
            TRRD(rb[S][2 * kb],     bd); \
            TRRD(rb[S][2 * kb + 1], bd + 128); } }
#define MFMA_JB(JB, S) { \
        f32x4 d4 = (f32x4){0.f, 0.f, 0.f, 0.f}; \
        _Pragma("unroll") \
        for (int kb = 0; kb < 4; ++kb) { \
            u32x4 tmp = (u32x4){rb[S][2 * kb].x, rb[S][2 * kb].y, rb[S][2 * kb + 1].x, rb[S][2 * kb + 1].y}; \
            short8 Bf = __builtin_bit_cast(short8, tmp); \
            d4 = __builtin_amdgcn_mfma_f32_16x16x32_bf16(A[kb], Bf, d4, 0, 0, 0); } \
        acc[JB] = d4; }

        ISSUE_B(0, 0);                 // outstanding: A(8) + B0(8) = 16
        ISSUE_B(1, 1);                 // 24
        WAITL8;                        // A + B0 complete (DS in-order), B1 in flight
        short8 A[4];
        #pragma unroll
        for (int kb = 0; kb < 4; ++kb) {
            u32x4 tmp = (u32x4){ra[2 * kb].x, ra[2 * kb].y, ra[2 * kb + 1].x, ra[2 * kb + 1].y};
            A[kb] = __builtin_bit_cast(short8, tmp);
        }
        MFMA_JB(0, 0);
        ISSUE_B(0, 2); WAITL8; MFMA_JB(1, 1);
        ISSUE_B(1, 3); WAITL8; MFMA_JB(2, 0);
        ISSUE_B(0, 4); WAITL8; MFMA_JB(3, 1);
        ISSUE_B(1, 5); WAITL8; MFMA_JB(4, 0);
        ISSUE_B(0, 6); WAITL8; MFMA_JB(5, 1);
        ISSUE_B(1, 7); WAITL8; MFMA_JB(6, 0);
        WAITL0;                MFMA_JB(7, 1);
#undef ISSUE_B
#undef MFMA_JB

        // ---- strip <- G_new (wave-private; D: row = gq*4+r, col = cc)
        #pragma unroll
        for (int jb = 0; jb < 8; ++jb) {
            uint32_t p0 = cvtpk(acc[jb][0], acc[jb][1]);
            uint32_t p1 = cvtpk(acc[jb][2], acc[jb][3]);
            *(uint2*)(strips + wv * STRIDE_S + (jb * 16 + cc) * 32 + gq * 8) = make_uint2(p0, p1);
        }
        // single barrier per step happens at top of next iteration (after pack)
    }

    // ---- export G row-major bf16 (verified round-5 path)
    uint32_t* gdst = gout + ((size_t)(b * NCH + c) << 13);
    #pragma unroll
    for (int kb = 0; kb < 4; ++kb) {
        u32x2 e0, e1;
        uint32_t ad = sbase + (uint32_t)(kb * 1024) + lt;
        TRRD(e0, ad);
        TRRD(e1, ad + 128);
        WAITL0;
        u32x4 o = (u32x4){e0.x, e0.y, e1.x, e1.y};
        *(u32x4*)(gdst + (size_t)((16 * wv + cc) * 64 + kb * 16 + gq * 4)) = o;
    }
}

// ---------------- Kernel 3: serial combine, 4 waves per batch (k-split) ----------------
// gamma (128 f32) <- gamma @ G_c, rescale by max (exact: S -= log(mr) for any mr).
__global__ __launch_bounds__(256, 1) void k_comb(
    const uint32_t* __restrict__ gtiles, // [B][NCH][8192] u32, G row-major bf16
    const int*   __restrict__ dur,
    const float* __restrict__ sp,        // [B,N]
    const float* __restrict__ e,         // [B,T,N]
    float* __restrict__ out)             // [B]
{
    const int b   = blockIdx.x;
    const int tid = threadIdx.x;
    const int wv  = tid >> 6;            // wave 0..3: k-range [32wv, 32wv+32)
    const int l   = tid & 63;            // output col pair (2l, 2l+1)
    const int d   = dur[b];
    const int nc  = (d - 1 + 7) >> 3;

    __shared__ float  gl[2][N_];
    __shared__ float2 part[4][64];

    float g0 = sp[b * N_ + 2 * l];
    float g1 = sp[b * N_ + 2 * l + 1];
    float S  = -(float)(d - 1) * LOG128;
    if (tid < 64) *(float2*)&gl[0][2 * l] = make_float2(g0, g1);
    __syncthreads();

    const uint32_t* gb = gtiles + (((size_t)b * NCH) << 13) + l;
    uint32_t cwA[32], cwB[32];
    int p = 0;

#define LOADCH(P, C) { \
    const uint32_t* gp_ = gb + ((size_t)(C) << 13); \
    _Pragma("unroll") \
    for (int kk = 0; kk < 32; ++kk) P[kk] = gp_[(size_t)(wv * 32 + kk) * 64]; }

#define CSTEP(CUR, NXT) { \
    if (c + 1 < nc) LOADCH(NXT, c + 1); \
    float n0 = 0.f, n1 = 0.f; \
    _Pragma("unroll") \
    for (int kk = 0; kk < 32; ++kk) { \
        float gk = gl[p][wv * 32 + kk]; \
        n0 = fmaf(blo(CUR[kk]), gk, n0); \
        n1 = fmaf(bhi(CUR[kk]), gk, n1); } \
    part[wv][l] = make_float2(n0, n1); \
    __syncthreads(); \
    float2 q0 = part[0][l], q1 = part[1][l], q2 = part[2][l], q3 = part[3][l]; \
    float s0 = (q0.x + q1.x) + (q2.x + q3.x); \
    float s1 = (q0.y + q1.y) + (q2.y + q3.y); \
    float mx = fmaxf(s0, s1); \
    _Pragma("unroll") \
    for (int of = 1; of < 64; of <<= 1) mx = fmaxf(mx, __shfl_xor(mx, of)); \
    float mr = __builtin_amdgcn_rcpf(mx); \
    g0 = s0 * mr; g1 = s1 * mr; \
    S -= __logf(mr); \
    if (tid < 64) *(float2*)&gl[p ^ 1][2 * l] = make_float2(g0, g1); \
    __syncthreads(); \
    p ^= 1; \
}

    if (nc > 0) {
        LOADCH(cwA, 0);
        int c = 0;
        while (true) {
            CSTEP(cwA, cwB); ++c; if (c >= nc) break;
            CSTEP(cwB, cwA); ++c; if (c >= nc) break;
        }
    }
#undef LOADCH
#undef CSTEP

    // ---- final: out[b] = S + log(sum_j gamma[j] * e[d-1][j])  (all waves identical; wave 0 writes)
    float e0 = e[((size_t)b * T_ + (d - 1)) * N_ + 2 * l];
    float e1 = e[((size_t)b * T_ + (d - 1)) * N_ + 2 * l + 1];
    float sv = g0 * e0 + g1 * e1;
    #pragma unroll
    for (int of = 1; of < 64; of <<= 1) sv += __shfl_xor(sv, of);
    if (tid == 0) out[b] = S + logf(sv);
}

extern "C" void kernel_launch(void* const* d_in, const int* in_sizes, int n_in,
                              void* d_out, int out_size, void* d_ws, size_t ws_size,
                              hipStream_t stream) {
    const float* obs   = (const float*)d_in[0];   // [B,T,K]
    const int*   dur   = (const int*)  d_in[1];   // [B]
    const float* trans = (const float*)d_in[2];   // [T,B,N,N]
    const float* sp    = (const float*)d_in[3];   // [B,N]
    const float* W     = (const float*)d_in[4];   // [K,N]
    const float* bias  = (const float*)d_in[5];   // [N]
    float* out = (float*)d_out;

    float* e = (float*)d_ws;                                   // 1 MB
    uint32_t* gout = (uint32_t*)((char*)d_ws + (size_t)B_ * T_ * N_ * 4);  // 8 MB

    hipLaunchKernelGGL(k_emit,  dim3(B_ * T_),  dim3(128), 0, stream, obs, dur, W, bias, e);
    hipLaunchKernelGGL(k_chunk, dim3(B_ * NCH), dim3(512), 0, stream, trans, dur, e, gout);
    hipLaunchKernelGGL(k_comb,  dim3(B_),       dim3(256), 0, stream, gout, dur, sp, e, out);
}

// Round 9
// 69.080 us; speedup vs baseline: 4.8304x; 1.0158x over previous
//
#include <hip/hip_runtime.h>
#include <math.h>
#include <stdint.h>

#define B_ 8
#define T_ 256
#define N_ 128
#define K_ 64
#define NCH 32
#define LOG128 4.852030263919617f
#define STRIDE_S 4128   // padded 16-col-block / strip stride in bytes

typedef __attribute__((ext_vector_type(2))) unsigned int u32x2;
typedef __attribute__((ext_vector_type(4))) unsigned int u32x4;
typedef __attribute__((ext_vector_type(4))) float f32x4;
typedef __attribute__((ext_vector_type(8))) short short8;

__device__ __forceinline__ uint32_t cvtpk(float lo, float hi) {
    uint32_t r;
    asm("v_cvt_pk_bf16_f32 %0, %1, %2" : "=v"(r) : "v"(lo), "v"(hi));
    return r;
}
__device__ __forceinline__ float blo(uint32_t w) { return __uint_as_float(w << 16); }
__device__ __forceinline__ float bhi(uint32_t w) { return __uint_as_float(w & 0xffff0000u); }

#define TRRD(dst, addr) asm volatile("ds_read_b64_tr_b16 %0, %1" : "=v"(dst) : "v"(addr) : "memory")
// lgkmcnt is a 4-bit field: counts must be <= 15
#define WAITL8  { asm volatile("s_waitcnt lgkmcnt(8)"  ::: "memory"); __builtin_amdgcn_sched_barrier(0); }
#define WAITL0  { asm volatile("s_waitcnt lgkmcnt(0)"  ::: "memory"); __builtin_amdgcn_sched_barrier(0); }
// Barrier with LDS-only drain: keeps global prefetch loads in flight across it
// (__syncthreads() would emit s_waitcnt vmcnt(0) and drain them — the m97 stall).
#define BARRIER_LG() { asm volatile("s_waitcnt lgkmcnt(0)" ::: "memory"); \
                       __builtin_amdgcn_s_barrier(); \
                       __builtin_amdgcn_sched_barrier(0); }

// ---------------- Kernel 1: emission probabilities (softmax of obs @ W + b) ----------------
__global__ __launch_bounds__(128) void k_emit(
    const float* __restrict__ obs,    // [B,T,K]
    const int*   __restrict__ dur,    // [B]
    const float* __restrict__ W,      // [K,N]
    const float* __restrict__ bias,   // [N]
    float* __restrict__ e)            // [B,T,N] softmax probs
{
    int bt = blockIdx.x;
    int b  = bt >> 8;
    int t  = bt & 255;
    if (t >= dur[b]) return;
    int n = threadIdx.x;
    __shared__ float o[K_];
    __shared__ float wmax[2];
    __shared__ float wsum[2];
    if (n < K_) o[n] = obs[(size_t)bt * K_ + n];
    __syncthreads();
    float acc = bias[n];
    #pragma unroll
    for (int k = 0; k < K_; ++k)
        acc = fmaf(o[k], W[k * N_ + n], acc);
    float m = acc;
    #pragma unroll
    for (int off = 32; off; off >>= 1) m = fmaxf(m, __shfl_xor(m, off));
    int w = n >> 6;
    if ((n & 63) == 0) wmax[w] = m;
    __syncthreads();
    float M = fmaxf(wmax[0], wmax[1]);
    float ex = expf(acc - M);
    float s = ex;
    #pragma unroll
    for (int off = 32; off; off >>= 1) s += __shfl_xor(s, off);
    if ((n & 63) == 0) wsum[w] = s;
    __syncthreads();
    float S = wsum[0] + wsum[1];
    e[(size_t)bt * N_ + n] = ex / S;
}

// ---------------- Kernel 2: chunk matrix products via MFMA ----------------
// Block (b,c): G_c = Prod_{t=t0..te} C_t, C_t = 128*diag(e[t-1])*rownorm(trans[t,b]).
// Math/layout identical to the round-5 verified kernel; 1 barrier/step with
// LDS-only drain (staging prefetch stays in flight through the MFMA phase),
// 2-deep counted-lgkmcnt tr_read pipeline in the MFMA phase.
__global__ __launch_bounds__(512, 1) void k_chunk(
    const float* __restrict__ trans,  // [T,B,N,N]
    const int*   __restrict__ dur,
    const float* __restrict__ e,      // [B,T,N]
    uint32_t* __restrict__ gout)      // [B][NCH][8192] u32
{
    const int bc = blockIdx.x;
    const int b  = bc & 7;
    const int c  = bc >> 3;
    const int d  = dur[b];
    const int t0 = c * 8 + 1;
    if (t0 > d - 1) return;
    int te = c * 8 + 8; if (te > d - 1) te = d - 1;

    const int tid  = threadIdx.x;
    const int lane = tid & 63;
    const int wv   = tid >> 6;
    const int cc   = lane & 15;
    const int gq   = lane >> 4;

    __shared__ __align__(16) uint8_t ldsC[2][8 * STRIDE_S];  // C' col-blocks, double-buffered
    __shared__ __align__(16) uint8_t strips[8 * STRIDE_S];   // per-wave G strips

    // strip init: G = Identity. strip[k][m] = G[16wv+m][k]
    {
        uint32_t* sw = (uint32_t*)(strips + wv * STRIDE_S);
        #pragma unroll
        for (int i = 0; i < 16; ++i) sw[lane + i * 64] = 0;
        if (lane < 16)
            ((uint16_t*)(strips + wv * STRIDE_S))[(16 * wv + lane) * 16 + lane] = 0x3F80u;
    }

    const uint32_t sbase = (uint32_t)(uintptr_t)&strips[wv * STRIDE_S];
    const uint32_t lt    = (uint32_t)(cc * 2 + gq * 256);
    const int row0 = tid >> 5;                 // rows row0 + 16i
    const int jbp  = (tid & 31) >> 2;          // pack col-block
    const int cc0  = (tid & 3) << 2;           // pack col quad

    f32x4 acc[8];

    // preload v, e for t0
    float4 v[8];
    float  ev[8];
    {
        const float4* gp = (const float4*)(trans + (((size_t)t0 * B_ + b) << 14));
        #pragma unroll
        for (int i = 0; i < 8; ++i) v[i] = gp[tid + i * 512];
        #pragma unroll
        for (int i = 0; i < 8; ++i)
            ev[i] = e[((size_t)b * T_ + (t0 - 1)) * N_ + row0 + i * 16];
    }

    int buf = 0;
    for (int t = t0; t <= te; ++t, buf ^= 1) {
        uint8_t* cb = ldsC[buf];
        const uint32_t cbase = (uint32_t)(uintptr_t)cb;

        // ---- row L1 sums via 32-lane shuffle; inv = 128*e/rowsum; pack bf16 to ldsC[buf]
        #pragma unroll
        for (int i = 0; i < 8; ++i) {
            float ps = (v[i].x + v[i].y) + (v[i].z + v[i].w);
            ps += __shfl_xor(ps, 1);
            ps += __shfl_xor(ps, 2);
            ps += __shfl_xor(ps, 4);
            ps += __shfl_xor(ps, 8);
            ps += __shfl_xor(ps, 16);
            float sc = 128.0f * ev[i] / ps;
            uint32_t p0 = cvtpk(v[i].x * sc, v[i].y * sc);
            uint32_t p1 = cvtpk(v[i].z * sc, v[i].w * sc);
            *(uint2*)(cb + jbp * STRIDE_S + (row0 + i * 16) * 32 + cc0 * 2) = make_uint2(p0, p1);
        }

        // ---- prefetch v, e for t+1 (issued before the barrier; stays in flight
        //      through the MFMA phase thanks to the LDS-only drain)
        if (t < te) {
            const float4* gp = (const float4*)(trans + (((size_t)(t + 1) * B_ + b) << 14));
            #pragma unroll
            for (int i = 0; i < 8; ++i) v[i] = gp[tid + i * 512];
            #pragma unroll
            for (int i = 0; i < 8; ++i)
                ev[i] = e[((size_t)b * T_ + t) * N_ + row0 + i * 16];
        }
        BARRIER_LG();

        // ---- MFMA phase: A from own strip, B from ldsC[buf]; 2-deep tr_read pipeline
        u32x2 ra[8];
        #pragma unroll
        for (int kb = 0; kb < 4; ++kb) {
            uint32_t ad = sbase + (uint32_t)(kb * 1024) + lt;
            TRRD(ra[2 * kb],     ad);
            TRRD(ra[2 * kb + 1], ad + 128);
        }
        u32x2 rb[2][8];
#define ISSUE_B(S, JB) { \
        _Pragma("unroll") \
        for (int kb = 0; kb < 4; ++kb) { \
            uint32_t bd = cbase + (uint32_t)((JB) * STRIDE_S + kb * 1024) + lt; \
            TRRD(rb[S][2 * kb],     bd); \
            TRRD(rb[S][2 * kb + 1], bd + 128); } }
#define MFMA_JB(JB, S) { \
        f32x4 d4 = (f32x4){0.f, 0.f, 0.f, 0.f}; \
        _Pragma("unroll") \
        for (int kb = 0; kb < 4; ++kb) { \
            u32x4 tmp = (u32x4){rb[S][2 * kb].x, rb[S][2 * kb].y, rb[S][2 * kb + 1].x, rb[S][2 * kb + 1].y}; \
            short8 Bf = __builtin_bit_cast(short8, tmp); \
            d4 = __builtin_amdgcn_mfma_f32_16x16x32_bf16(A[kb], Bf, d4, 0, 0, 0); } \
        acc[JB] = d4; }

        ISSUE_B(0, 0);                 // outstanding: A(8) + B0(8) = 16
        ISSUE_B(1, 1);                 // 24
        WAITL8;                        // A + B0 complete (DS in-order), B1 in flight
        short8 A[4];
        #pragma unroll
        for (int kb = 0; kb < 4; ++kb) {
            u32x4 tmp = (u32x4){ra[2 * kb].x, ra[2 * kb].y, ra[2 * kb + 1].x, ra[2 * kb + 1].y};
            A[kb] = __builtin_bit_cast(short8, tmp);
        }
        MFMA_JB(0, 0);
        ISSUE_B(0, 2); WAITL8; MFMA_JB(1, 1);
        ISSUE_B(1, 3); WAITL8; MFMA_JB(2, 0);
        ISSUE_B(0, 4); WAITL8; MFMA_JB(3, 1);
        ISSUE_B(1, 5); WAITL8; MFMA_JB(4, 0);
        ISSUE_B(0, 6); WAITL8; MFMA_JB(5, 1);
        ISSUE_B(1, 7); WAITL8; MFMA_JB(6, 0);
        WAITL0;                MFMA_JB(7, 1);
#undef ISSUE_B
#undef MFMA_JB

        // ---- strip <- G_new (wave-private; D: row = gq*4+r, col = cc)
        #pragma unroll
        for (int jb = 0; jb < 8; ++jb) {
            uint32_t p0 = cvtpk(acc[jb][0], acc[jb][1]);
            uint32_t p1 = cvtpk(acc[jb][2], acc[jb][3]);
            *(uint2*)(strips + wv * STRIDE_S + (jb * 16 + cc) * 32 + gq * 8) = make_uint2(p0, p1);
        }
        // single barrier per step happens at top of next iteration (after pack)
    }

    // ---- export G row-major bf16 (verified round-5 path)
    uint32_t* gdst = gout + ((size_t)(b * NCH + c) << 13);
    #pragma unroll
    for (int kb = 0; kb < 4; ++kb) {
        u32x2 e0, e1;
        uint32_t ad = sbase + (uint32_t)(kb * 1024) + lt;
        TRRD(e0, ad);
        TRRD(e1, ad + 128);
        WAITL0;
        u32x4 o = (u32x4){e0.x, e0.y, e1.x, e1.y};
        *(u32x4*)(gdst + (size_t)((16 * wv + cc) * 64 + kb * 16 + gq * 4)) = o;
    }
}

// ---------------- Kernel 3: serial combine, 4 waves per batch (k-split) ----------------
// gamma (128 f32) <- gamma @ G_c, rescale by max (exact: S -= log(mr) for any mr).
// Depth-2 register prefetch (3-buffer rotation), ONE LDS-only-drain barrier per
// chunk (part double-buffered; every wave writes gl so it reads its own writes).
__global__ __launch_bounds__(256, 1) void k_comb(
    const uint32_t* __restrict__ gtiles, // [B][NCH][8192] u32, G row-major bf16
    const int*   __restrict__ dur,
    const float* __restrict__ sp,        // [B,N]
    const float* __restrict__ e,         // [B,T,N]
    float* __restrict__ out)             // [B]
{
    const int b   = blockIdx.x;
    const int tid = threadIdx.x;
    const int wv  = tid >> 6;            // wave 0..3: k-range [32wv, 32wv+32)
    const int l   = tid & 63;            // output col pair (2l, 2l+1)
    const int d   = dur[b];
    const int nc  = (d - 1 + 7) >> 3;

    __shared__ float  gl[2][N_];
    __shared__ float2 part[2][4][64];

    float g0 = sp[b * N_ + 2 * l];
    float g1 = sp[b * N_ + 2 * l + 1];
    float S  = -(float)(d - 1) * LOG128;
    // every wave writes the full gl[0] (identical values) -> reads its own writes
    *(float2*)&gl[0][2 * l] = make_float2(g0, g1);

    const uint32_t* gb = gtiles + (((size_t)b * NCH) << 13) + l;
    uint32_t cwA[32], cwB[32], cwC[32];
    int p = 0;

#define LOADCH(P, C) { \
    const uint32_t* gp_ = gb + ((size_t)(C) << 13); \
    _Pragma("unroll") \
    for (int kk = 0; kk < 32; ++kk) P[kk] = gp_[(size_t)(wv * 32 + kk) * 64]; }

#define CSTEP(CUR, NXT, CIDX) { \
    if ((CIDX) + 2 < nc) LOADCH(NXT, (CIDX) + 2); \
    float n0a = 0.f, n0b = 0.f, n1a = 0.f, n1b = 0.f; \
    _Pragma("unroll") \
    for (int kk = 0; kk < 32; kk += 2) { \
        float gk0 = gl[p][wv * 32 + kk]; \
        float gk1 = gl[p][wv * 32 + kk + 1]; \
        n0a = fmaf(blo(CUR[kk]),     gk0, n0a); \
        n1a = fmaf(bhi(CUR[kk]),     gk0, n1a); \
        n0b = fmaf(blo(CUR[kk + 1]), gk1, n0b); \
        n1b = fmaf(bhi(CUR[kk + 1]), gk1, n1b); } \
    part[p][wv][l] = make_float2(n0a + n0b, n1a + n1b); \
    BARRIER_LG(); \
    float2 q0 = part[p][0][l], q1 = part[p][1][l], q2 = part[p][2][l], q3 = part[p][3][l]; \
    float s0 = (q0.x + q1.x) + (q2.x + q3.x); \
    float s1 = (q0.y + q1.y) + (q2.y + q3.y); \
    float mx = fmaxf(s0, s1); \
    _Pragma("unroll") \
    for (int of = 1; of < 64; of <<= 1) mx = fmaxf(mx, __shfl_xor(mx, of)); \
    float mr = __builtin_amdgcn_rcpf(mx); \
    g0 = s0 * mr; g1 = s1 * mr; \
    S -= __logf(mr); \
    *(float2*)&gl[p ^ 1][2 * l] = make_float2(g0, g1); \
    p ^= 1; \
}

    if (nc > 0) {
        LOADCH(cwA, 0);
        if (nc > 1) LOADCH(cwB, 1);
        int c = 0;
        while (true) {
            CSTEP(cwA, cwC, c); ++c; if (c >= nc) break;
            CSTEP(cwB, cwA, c); ++c; if (c >= nc) break;
            CSTEP(cwC, cwB, c); ++c; if (c >= nc) break;
        }
    }
#undef LOADCH
#undef CSTEP

    // ---- final: out[b] = S + log(sum_j gamma[j] * e[d-1][j])  (all waves identical; tid 0 writes)
    float e0 = e[((size_t)b * T_ + (d - 1)) * N_ + 2 * l];
    float e1 = e[((size_t)b * T_ + (d - 1)) * N_ + 2 * l + 1];
    float sv = g0 * e0 + g1 * e1;
    #pragma unroll
    for (int of = 1; of < 64; of <<= 1) sv += __shfl_xor(sv, of);
    if (tid == 0) out[b] = S + logf(sv);
}

extern "C" void kernel_launch(void* const* d_in, const int* in_sizes, int n_in,
                              void* d_out, int out_size, void* d_ws, size_t ws_size,
                              hipStream_t stream) {
    const float* obs   = (const float*)d_in[0];   // [B,T,K]
    const int*   dur   = (const int*)  d_in[1];   // [B]
    const float* trans = (const float*)d_in[2];   // [T,B,N,N]
    const float* sp    = (const float*)d_in[3];   // [B,N]
    const float* W     = (const float*)d_in[4];   // [K,N]
    const float* bias  = (const float*)d_in[5];   // [N]
    float* out = (float*)d_out;

    float* e = (float*)d_ws;                                   // 1 MB
    uint32_t* gout = (uint32_t*)((char*)d_ws + (size_t)B_ * T_ * N_ * 4);  // 8 MB

    hipLaunchKernelGGL(k_emit,  dim3(B_ * T_),  dim3(128), 0, stream, obs, dur, W, bias, e);
    hipLaunchKernelGGL(k_chunk, dim3(B_ * NCH), dim3(512), 0, stream, trans, dur, e, gout);
    hipLaunchKernelGGL(k_comb,  dim3(B_),       dim3(256), 0, stream, gout, dur, sp, e, out);
}

// Round 10
// 67.595 us; speedup vs baseline: 4.9365x; 1.0220x over previous
//
#include <hip/hip_runtime.h>
#include <math.h>
#include <stdint.h>

#define B_ 8
#define T_ 256
#define N_ 128
#define K_ 64
#define NCH 32
#define LOG128 4.852030263919617f
#define STRIDE_S 4128   // padded 16-col-block / strip stride in bytes

typedef __attribute__((ext_vector_type(2))) unsigned int u32x2;
typedef __attribute__((ext_vector_type(4))) unsigned int u32x4;
typedef __attribute__((ext_vector_type(4))) float f32x4;
typedef __attribute__((ext_vector_type(8))) short short8;

__device__ __forceinline__ uint32_t cvtpk(float lo, float hi) {
    uint32_t r;
    asm("v_cvt_pk_bf16_f32 %0, %1, %2" : "=v"(r) : "v"(lo), "v"(hi));
    return r;
}
__device__ __forceinline__ float blo(uint32_t w) { return __uint_as_float(w << 16); }
__device__ __forceinline__ float bhi(uint32_t w) { return __uint_as_float(w & 0xffff0000u); }

#define TRRD(dst, addr) asm volatile("ds_read_b64_tr_b16 %0, %1" : "=v"(dst) : "v"(addr) : "memory")
// lgkmcnt is a 4-bit field: counts must be <= 15
#define WAITL8  { asm volatile("s_waitcnt lgkmcnt(8)"  ::: "memory"); __builtin_amdgcn_sched_barrier(0); }
#define WAITL0  { asm volatile("s_waitcnt lgkmcnt(0)"  ::: "memory"); __builtin_amdgcn_sched_barrier(0); }
// Barrier with LDS-only drain: keeps global prefetch loads in flight across it.
// The "memory" clobber also pins load issue order (loads can't sink past it).
#define BARRIER_LG() { asm volatile("s_waitcnt lgkmcnt(0)" ::: "memory"); \
                       __builtin_amdgcn_s_barrier(); \
                       __builtin_amdgcn_sched_barrier(0); }

// ---------------- Kernel 1: emission probabilities (softmax of obs @ W + b) ----------------
__global__ __launch_bounds__(128) void k_emit(
    const float* __restrict__ obs,    // [B,T,K]
    const int*   __restrict__ dur,    // [B]
    const float* __restrict__ W,      // [K,N]
    const float* __restrict__ bias,   // [N]
    float* __restrict__ e)            // [B,T,N] softmax probs
{
    int bt = blockIdx.x;
    int b  = bt >> 8;
    int t  = bt & 255;
    if (t >= dur[b]) return;
    int n = threadIdx.x;
    __shared__ float o[K_];
    __shared__ float wmax[2];
    __shared__ float wsum[2];
    if (n < K_) o[n] = obs[(size_t)bt * K_ + n];
    __syncthreads();
    float acc = bias[n];
    #pragma unroll
    for (int k = 0; k < K_; ++k)
        acc = fmaf(o[k], W[k * N_ + n], acc);
    float m = acc;
    #pragma unroll
    for (int off = 32; off; off >>= 1) m = fmaxf(m, __shfl_xor(m, off));
    int w = n >> 6;
    if ((n & 63) == 0) wmax[w] = m;
    __syncthreads();
    float M = fmaxf(wmax[0], wmax[1]);
    float ex = expf(acc - M);
    float s = ex;
    #pragma unroll
    for (int off = 32; off; off >>= 1) s += __shfl_xor(s, off);
    if ((n & 63) == 0) wsum[w] = s;
    __syncthreads();
    float S = wsum[0] + wsum[1];
    e[(size_t)bt * N_ + n] = ex / S;
}

// ---------------- Kernel 2: chunk matrix products via MFMA ----------------
// Block (b,c): G_c = Prod_{t=t0..te} C_t, C_t = 128*diag(e[t-1])*rownorm(trans[t,b]).
// Math/layout identical to the verified round-5 path. Depth-2 register tile
// prefetch (vA/vB): tile(t+2) is issued during staging of t, so HBM streams
// continuously instead of being gated once per step.
__global__ __launch_bounds__(512, 1) void k_chunk(
    const float* __restrict__ trans,  // [T,B,N,N]
    const int*   __restrict__ dur,
    const float* __restrict__ e,      // [B,T,N]
    uint32_t* __restrict__ gout)      // [B][NCH][8192] u32
{
    const int bc = blockIdx.x;
    const int b  = bc & 7;
    const int c  = bc >> 3;
    const int d  = dur[b];
    const int t0 = c * 8 + 1;
    if (t0 > d - 1) return;
    int te = c * 8 + 8; if (te > d - 1) te = d - 1;

    const int tid  = threadIdx.x;
    const int lane = tid & 63;
    const int wv   = tid >> 6;
    const int cc   = lane & 15;
    const int gq   = lane >> 4;

    __shared__ __align__(16) uint8_t ldsC[2][8 * STRIDE_S];  // C' col-blocks, double-buffered
    __shared__ __align__(16) uint8_t strips[8 * STRIDE_S];   // per-wave G strips

    // strip init: G = Identity. strip[k][m] = G[16wv+m][k]
    {
        uint32_t* sw = (uint32_t*)(strips + wv * STRIDE_S);
        #pragma unroll
        for (int i = 0; i < 16; ++i) sw[lane + i * 64] = 0;
        if (lane < 16)
            ((uint16_t*)(strips + wv * STRIDE_S))[(16 * wv + lane) * 16 + lane] = 0x3F80u;
    }

    const uint32_t sbase = (uint32_t)(uintptr_t)&strips[wv * STRIDE_S];
    const uint32_t lt    = (uint32_t)(cc * 2 + gq * 256);
    const int row0 = tid >> 5;                 // rows row0 + 16i
    const int jbp  = (tid & 31) >> 2;          // pack col-block
    const int cc0  = (tid & 3) << 2;           // pack col quad

    // depth-2 prefetch buffers
    float4 vA[8], vB[8];
    float  eA[8], eB[8];
    {
        const float4* gp = (const float4*)(trans + (((size_t)t0 * B_ + b) << 14));
        #pragma unroll
        for (int i = 0; i < 8; ++i) vA[i] = gp[tid + i * 512];
        #pragma unroll
        for (int i = 0; i < 8; ++i)
            eA[i] = e[((size_t)b * T_ + (t0 - 1)) * N_ + row0 + i * 16];
    }
    if (t0 + 1 <= te) {
        const float4* gp = (const float4*)(trans + (((size_t)(t0 + 1) * B_ + b) << 14));
        #pragma unroll
        for (int i = 0; i < 8; ++i) vB[i] = gp[tid + i * 512];
        #pragma unroll
        for (int i = 0; i < 8; ++i)
            eB[i] = e[((size_t)b * T_ + t0) * N_ + row0 + i * 16];
    }

    int buf = 0;

#define ISSUE_B(S, JB) { \
        _Pragma("unroll") \
        for (int kb = 0; kb < 4; ++kb) { \
            uint32_t bd = cbase + (uint32_t)((JB) * STRIDE_S + kb * 1024) + lt; \
            TRRD(rb[S][2 * kb],     bd); \
            TRRD(rb[S][2 * kb + 1], bd + 128); } }
#define MFMA_JB(JB, S) { \
        f32x4 d4 = (f32x4){0.f, 0.f, 0.f, 0.f}; \
        _Pragma("unroll") \
        for (int kb = 0; kb < 4; ++kb) { \
            u32x4 tmp = (u32x4){rb[S][2 * kb].x, rb[S][2 * kb].y, rb[S][2 * kb + 1].x, rb[S][2 * kb + 1].y}; \
            short8 Bf = __builtin_bit_cast(short8, tmp); \
            d4 = __builtin_amdgcn_mfma_f32_16x16x32_bf16(A[kb], Bf, d4, 0, 0, 0); } \
        acc[JB] = d4; }

#define STEP(VC, EC) { \
    uint8_t* cb = ldsC[buf]; \
    const uint32_t cbase = (uint32_t)(uintptr_t)cb; \
    /* ---- staging: row L1 sums (32-lane shfl), scale 128*e*rcp(sum), pack bf16 */ \
    _Pragma("unroll") \
    for (int i = 0; i < 8; ++i) { \
        float ps = (VC[i].x + VC[i].y) + (VC[i].z + VC[i].w); \
        ps += __shfl_xor(ps, 1); \
        ps += __shfl_xor(ps, 2); \
        ps += __shfl_xor(ps, 4); \
        ps += __shfl_xor(ps, 8); \
        ps += __shfl_xor(ps, 16); \
        float sc = 128.0f * EC[i] * __builtin_amdgcn_rcpf(ps); \
        uint32_t p0 = cvtpk(VC[i].x * sc, VC[i].y * sc); \
        uint32_t p1 = cvtpk(VC[i].z * sc, VC[i].w * sc); \
        *(uint2*)(cb + jbp * STRIDE_S + (row0 + i * 16) * 32 + cc0 * 2) = make_uint2(p0, p1); \
    } \
    /* ---- depth-2 prefetch: tile(t+2) into the buffer just freed */ \
    if (t + 2 <= te) { \
        const float4* gp = (const float4*)(trans + (((size_t)(t + 2) * B_ + b) << 14)); \
        _Pragma("unroll") \
        for (int i = 0; i < 8; ++i) VC[i] = gp[tid + i * 512]; \
        _Pragma("unroll") \
        for (int i = 0; i < 8; ++i) \
            EC[i] = e[((size_t)b * T_ + (t + 1)) * N_ + row0 + i * 16]; \
    } \
    BARRIER_LG(); \
    /* ---- MFMA phase: A from own strip, B from ldsC[buf]; 2-deep tr_read pipeline */ \
    { \
        u32x2 ra[8]; \
        _Pragma("unroll") \
        for (int kb = 0; kb < 4; ++kb) { \
            uint32_t ad = sbase + (uint32_t)(kb * 1024) + lt; \
            TRRD(ra[2 * kb],     ad); \
            TRRD(ra[2 * kb + 1], ad + 128); \
        } \
        u32x2 rb[2][8]; \
        f32x4 acc[8]; \
        ISSUE_B(0, 0); \
        ISSUE_B(1, 1); \
        WAITL8; \
        short8 A[4]; \
        _Pragma("unroll") \
        for (int kb = 0; kb < 4; ++kb) { \
            u32x4 tmp = (u32x4){ra[2 * kb].x, ra[2 * kb].y, ra[2 * kb + 1].x, ra[2 * kb + 1].y}; \
            A[kb] = __builtin_bit_cast(short8, tmp); \
        } \
        MFMA_JB(0, 0); \
        ISSUE_B(0, 2); WAITL8; MFMA_JB(1, 1); \
        ISSUE_B(1, 3); WAITL8; MFMA_JB(2, 0); \
        ISSUE_B(0, 4); WAITL8; MFMA_JB(3, 1); \
        ISSUE_B(1, 5); WAITL8; MFMA_JB(4, 0); \
        ISSUE_B(0, 6); WAITL8; MFMA_JB(5, 1); \
        ISSUE_B(1, 7); WAITL8; MFMA_JB(6, 0); \
        WAITL0;                MFMA_JB(7, 1); \
        /* ---- strip <- G_new (wave-private; D: row = gq*4+r, col = cc) */ \
        _Pragma("unroll") \
        for (int jb = 0; jb < 8; ++jb) { \
            uint32_t p0 = cvtpk(acc[jb][0], acc[jb][1]); \
            uint32_t p1 = cvtpk(acc[jb][2], acc[jb][3]); \
            *(uint2*)(strips + wv * STRIDE_S + (jb * 16 + cc) * 32 + gq * 8) = make_uint2(p0, p1); \
        } \
    } \
    buf ^= 1; \
}

    int t = t0;
    while (true) {
        STEP(vA, eA); ++t; if (t > te) break;
        STEP(vB, eB); ++t; if (t > te) break;
    }
#undef STEP
#undef ISSUE_B
#undef MFMA_JB

    // ---- export G row-major bf16 (verified round-5 path)
    uint32_t* gdst = gout + ((size_t)(b * NCH + c) << 13);
    #pragma unroll
    for (int kb = 0; kb < 4; ++kb) {
        u32x2 e0, e1;
        uint32_t ad = sbase + (uint32_t)(kb * 1024) + lt;
        TRRD(e0, ad);
        TRRD(e1, ad + 128);
        WAITL0;
        u32x4 o = (u32x4){e0.x, e0.y, e1.x, e1.y};
        *(u32x4*)(gdst + (size_t)((16 * wv + cc) * 64 + kb * 16 + gq * 4)) = o;
    }
}

// ---------------- Kernel 3: serial combine, 4 waves per batch (k-split) ----------------
// gamma (128 f32) <- gamma @ G_c, rescale by max (exact: S -= log(mr) for any mr).
// Depth-3 register prefetch (4-buffer rotation), ONE LDS-only-drain barrier per
// chunk (part double-buffered; every wave writes gl so it reads its own writes).
__global__ __launch_bounds__(256, 1) void k_comb(
    const uint32_t* __restrict__ gtiles, // [B][NCH][8192] u32, G row-major bf16
    const int*   __restrict__ dur,
    const float* __restrict__ sp,        // [B,N]
    const float* __restrict__ e,         // [B,T,N]
    float* __restrict__ out)             // [B]
{
    const int b   = blockIdx.x;
    const int tid = threadIdx.x;
    const int wv  = tid >> 6;            // wave 0..3: k-range [32wv, 32wv+32)
    const int l   = tid & 63;            // output col pair (2l, 2l+1)
    const int d   = dur[b];
    const int nc  = (d - 1 + 7) >> 3;

    __shared__ float  gl[2][N_];
    __shared__ float2 part[2][4][64];

    float g0 = sp[b * N_ + 2 * l];
    float g1 = sp[b * N_ + 2 * l + 1];
    float S  = -(float)(d - 1) * LOG128;
    // every wave writes the full gl[0] (identical values) -> reads its own writes
    *(float2*)&gl[0][2 * l] = make_float2(g0, g1);

    const uint32_t* gb = gtiles + (((size_t)b * NCH) << 13) + l;
    uint32_t cwA[32], cwB[32], cwC[32], cwD[32];
    int p = 0;

#define LOADCH(P, C) { \
    const uint32_t* gp_ = gb + ((size_t)(C) << 13); \
    _Pragma("unroll") \
    for (int kk = 0; kk < 32; ++kk) P[kk] = gp_[(size_t)(wv * 32 + kk) * 64]; }

#define CSTEP(CUR, NXT, CIDX) { \
    if ((CIDX) + 3 < nc) LOADCH(NXT, (CIDX) + 3); \
    float n0a = 0.f, n0b = 0.f, n1a = 0.f, n1b = 0.f; \
    _Pragma("unroll") \
    for (int kk = 0; kk < 32; kk += 2) { \
        float gk0 = gl[p][wv * 32 + kk]; \
        float gk1 = gl[p][wv * 32 + kk + 1]; \
        n0a = fmaf(blo(CUR[kk]),     gk0, n0a); \
        n1a = fmaf(bhi(CUR[kk]),     gk0, n1a); \
        n0b = fmaf(blo(CUR[kk + 1]), gk1, n0b); \
        n1b = fmaf(bhi(CUR[kk + 1]), gk1, n1b); } \
    part[p][wv][l] = make_float2(n0a + n0b, n1a + n1b); \
    BARRIER_LG(); \
    float2 q0 = part[p][0][l], q1 = part[p][1][l], q2 = part[p][2][l], q3 = part[p][3][l]; \
    float s0 = (q0.x + q1.x) + (q2.x + q3.x); \
    float s1 = (q0.y + q1.y) + (q2.y + q3.y); \
    float mx = fmaxf(s0, s1); \
    _Pragma("unroll") \
    for (int of = 1; of < 64; of <<= 1) mx = fmaxf(mx, __shfl_xor(mx, of)); \
    float mr = __builtin_amdgcn_rcpf(mx); \
    g0 = s0 * mr; g1 = s1 * mr; \
    S -= __logf(mr); \
    *(float2*)&gl[p ^ 1][2 * l] = make_float2(g0, g1); \
    p ^= 1; \
}

    if (nc > 0) {
        LOADCH(cwA, 0);
        if (nc > 1) LOADCH(cwB, 1);
        if (nc > 2) LOADCH(cwC, 2);
        int c = 0;
        while (true) {
            CSTEP(cwA, cwD, c); ++c; if (c >= nc) break;
            CSTEP(cwB, cwA, c); ++c; if (c >= nc) break;
            CSTEP(cwC, cwB, c); ++c; if (c >= nc) break;
            CSTEP(cwD, cwC, c); ++c; if (c >= nc) break;
        }
    }
#undef LOADCH
#undef CSTEP

    // ---- final: out[b] = S + log(sum_j gamma[j] * e[d-1][j])  (all waves identical; tid 0 writes)
    float e0 = e[((size_t)b * T_ + (d - 1)) * N_ + 2 * l];
    float e1 = e[((size_t)b * T_ + (d - 1)) * N_ + 2 * l + 1];
    float sv = g0 * e0 + g1 * e1;
    #pragma unroll
    for (int of = 1; of < 64; of <<= 1) sv += __shfl_xor(sv, of);
    if (tid == 0) out[b] = S + logf(sv);
}

extern "C" void kernel_launch(void* const* d_in, const int* in_sizes, int n_in,
                              void* d_out, int out_size, void* d_ws, size_t ws_size,
                              hipStream_t stream) {
    const float* obs   = (const float*)d_in[0];   // [B,T,K]
    const int*   dur   = (const int*)  d_in[1];   // [B]
    const float* trans = (const float*)d_in[2];   // [T,B,N,N]
    const float* sp    = (const float*)d_in[3];   // [B,N]
    const float* W     = (const float*)d_in[4];   // [K,N]
    const float* bias  = (const float*)d_in[5];   // [N]
    float* out = (float*)d_out;

    float* e = (float*)d_ws;                                   // 1 MB
    uint32_t* gout = (uint32_t*)((char*)d_ws + (size_t)B_ * T_ * N_ * 4);  // 8 MB

    hipLaunchKernelGGL(k_emit,  dim3(B_ * T_),  dim3(128), 0, stream, obs, dur, W, bias, e);
    hipLaunchKernelGGL(k_chunk, dim3(B_ * NCH), dim3(512), 0, stream, trans, dur, e, gout);
    hipLaunchKernelGGL(k_comb,  dim3(B_),       dim3(256), 0, stream, gout, dur, sp, e, out);
}